// Round 8
// baseline (449.816 us; speedup 1.0000x reference)
//
#include <hip/hip_runtime.h>

#define TILE_ATOMS 10000               // 10 tiles for 100K atoms
#define TILE_FLOATS (TILE_ATOMS * 4)   // 160000 B LDS = full CU capacity
#define BLOCK 1024
#define CPX 3                          // chunks per XCD
#define CHUNKS 24                      // 8 XCDs * CPX -> grid 240
#define RSQRT2 0.70710678118654752440f

typedef float v2f __attribute__((ext_vector_type(2)));

// Packed 2xf32 memory-side atomic add where the toolchain exposes it on
// gfx950; otherwise the r6-proven scalar pair. (r7 lesson: the hand-written
// "global_atomic_pk_add_f32" mnemonic does not assemble on gfx950.)
__device__ __forceinline__ void atomic_add2(float* p, float a, float b) {
#if __has_builtin(__builtin_amdgcn_global_atomic_fadd_v2f32)
    v2f v = {a, b};
    __builtin_amdgcn_global_atomic_fadd_v2f32((v2f*)p, v);
#else
    unsafeAtomicAdd(p + 0, a);
    unsafeAtomicAdd(p + 1, b);
#endif
}

// Detect whether neighbor_indices is int64 or int32 (odd u32 words all zero
// => int64 high halves). Replay-safe: value identical every call.
__global__ void detect_idx64_kernel(const unsigned int* __restrict__ idx_u32,
                                    int* __restrict__ flag) {
    __shared__ int nonzero;
    if (threadIdx.x == 0) nonzero = 0;
    __syncthreads();
    unsigned int v = idx_u32[2 * (threadIdx.x +   0) + 1]
                   | idx_u32[2 * (threadIdx.x + 256) + 1]
                   | idx_u32[2 * (threadIdx.x + 512) + 1]
                   | idx_u32[2 * (threadIdx.x + 768) + 1];
    if (v != 0u) atomicAdd(&nonzero, 1);
    __syncthreads();
    if (threadIdx.x == 0) *flag = (nonzero == 0) ? 1 : 0;  // 1 => int64
}

__device__ __forceinline__ void side_atomics(float* __restrict__ tile,
                                             unsigned r, float4 g, float q) {
    atomicAdd(&tile[r * 4 + 0], g.x * q);
    atomicAdd(&tile[r * 4 + 1], g.y * q);
    atomicAdd(&tile[r * 4 + 2], g.z * q);
    atomicAdd(&tile[r * 4 + 3], g.w * q);
}

// 8-deep scan: 8 idx + 8 dist stream loads issued up front (16 outstanding
// VMEM per wave -> hides the L2 window latency r6 showed to be the limiter),
// then hit work in two 4-groups (gather liveness capped at 8 float4 to stay
// under the 128-VGPR cap of 16 waves/CU).
template <bool F64>
__device__ __forceinline__ void scan_chunk(
    const void* __restrict__ idx, const float* __restrict__ dist,
    const float4* __restrict__ charges, float* __restrict__ tile,
    int tbase, int e0, int e1)
{
    constexpr int DEPTH = 8;
    int e = e0 + (int)threadIdx.x;
    for (; e + (DEPTH - 1) * BLOCK < e1; e += DEPTH * BLOCK) {
        int a[DEPTH], b[DEPTH];
        float d[DEPTH], q[DEPTH];
        #pragma unroll
        for (int k = 0; k < DEPTH; ++k) {
            if (F64) {
                longlong2 w = ((const longlong2*)idx)[e + k * BLOCK];
                a[k] = (int)w.x; b[k] = (int)w.y;
            } else {
                int2 w = ((const int2*)idx)[e + k * BLOCK];
                a[k] = w.x; b[k] = w.y;
            }
        }
        #pragma unroll
        for (int k = 0; k < DEPTH; ++k) d[k] = dist[e + k * BLOCK];
        #pragma unroll
        for (int k = 0; k < DEPTH; ++k)
            q[k] = 0.5f * erfcf(d[k] * RSQRT2) * __builtin_amdgcn_rcpf(d[k]);

        #pragma unroll
        for (int g = 0; g < 2; ++g) {       // two 4-groups: gathers then atomics
            unsigned ri[4], rj[4];
            float4 gi[4], gj[4];
            #pragma unroll
            for (int k = 0; k < 4; ++k) {
                int kk = g * 4 + k;
                ri[k] = (unsigned)(a[kk] - tbase);
                rj[k] = (unsigned)(b[kk] - tbase);
                if (ri[k] < TILE_ATOMS) gi[k] = charges[b[kk]];
                if (rj[k] < TILE_ATOMS) gj[k] = charges[a[kk]];
            }
            #pragma unroll
            for (int k = 0; k < 4; ++k) {
                int kk = g * 4 + k;
                if (ri[k] < TILE_ATOMS) side_atomics(tile, ri[k], gi[k], q[kk]);
                if (rj[k] < TILE_ATOMS) side_atomics(tile, rj[k], gj[k], q[kk]);
            }
        }
    }
    for (; e < e1; e += BLOCK) {
        int a, b;
        if (F64) { longlong2 w = ((const longlong2*)idx)[e]; a = (int)w.x; b = (int)w.y; }
        else     { int2      w = ((const int2*)idx)[e];      a = w.x;      b = w.y; }
        unsigned ri = (unsigned)(a - tbase), rj = (unsigned)(b - tbase);
        if (ri < TILE_ATOMS || rj < TILE_ATOMS) {
            float d = dist[e];
            float q = 0.5f * erfcf(d * RSQRT2) * __builtin_amdgcn_rcpf(d);
            if (ri < TILE_ATOMS) side_atomics(tile, ri, charges[b], q);
            if (rj < TILE_ATOMS) side_atomics(tile, rj, charges[a], q);
        }
    }
}

// Block (tile t, chunk c); XCD-affine chunk mapping keeps the moving read
// window in one XCD's L2 (r5/r6: FETCH 334->44MB). LDS-accumulate, flush via
// HW atomics (replay-safe; plain cross-kernel stores are NOT — r3 lesson).
__global__ __launch_bounds__(BLOCK, 1) void fused_tile_kernel(
    const float4* __restrict__ charges, const void* __restrict__ idx,
    const float* __restrict__ dist, float* __restrict__ out,
    const int* __restrict__ flag64,
    int n_edges, int n_atoms, int ntiles, int epc)
{
    __shared__ float tile[TILE_FLOATS];
    int x  = blockIdx.x & 7;              // XCD (round-robin dispatch, m09)
    int m  = blockIdx.x >> 3;
    int t  = m % ntiles;
    int cw = m / ntiles;                  // 0..CPX-1
    int c  = x * CPX + cw;
    int tbase = t * TILE_ATOMS;
    for (int i = threadIdx.x; i < TILE_FLOATS; i += BLOCK) tile[i] = 0.f;
    bool f64 = (*flag64 != 0);
    __syncthreads();

    int e0 = c * epc;
    int e1 = min(n_edges, e0 + epc);
    if (f64) scan_chunk<true >(idx, dist, charges, tile, tbase, e0, e1);
    else     scan_chunk<false>(idx, dist, charges, tile, tbase, e0, e1);
    __syncthreads();

    // Flush LDS tile -> global (2 packed ops/row when available, else 4).
    const float4* src = (const float4*)tile;
    for (int r = threadIdx.x; r < TILE_ATOMS; r += BLOCK) {
        int a = tbase + r;
        if (a >= n_atoms) break;
        float4 v = src[r];
        if (v.x != 0.f || v.y != 0.f || v.z != 0.f || v.w != 0.f) {
            float* o = out + (size_t)a * 4;
            atomic_add2(o + 0, v.x, v.y);
            atomic_add2(o + 2, v.z, v.w);
        }
    }
}

extern "C" void kernel_launch(void* const* d_in, const int* in_sizes, int n_in,
                              void* d_out, int out_size, void* d_ws, size_t ws_size,
                              hipStream_t stream) {
    const float4* charges = (const float4*)d_in[0];
    const void*   idx     = d_in[1];
    const float*  dist    = (const float*)d_in[2];
    int n_edges = in_sizes[2];
    int n_atoms = in_sizes[0] / 4;
    int ntiles  = (n_atoms + TILE_ATOMS - 1) / TILE_ATOMS;   // 10
    int epc     = (n_edges + CHUNKS - 1) / CHUNKS;
    int* flag   = (int*)d_ws;

    (void)hipMemsetAsync(d_out, 0, (size_t)out_size * sizeof(float), stream);
    detect_idx64_kernel<<<1, 256, 0, stream>>>((const unsigned int*)idx, flag);
    fused_tile_kernel<<<ntiles * CHUNKS, BLOCK, 0, stream>>>(
        charges, idx, dist, (float*)d_out, flag, n_edges, n_atoms, ntiles, epc);
}

// Round 9
// 407.611 us; speedup vs baseline: 1.1035x; 1.1035x over previous
//
#include <hip/hip_runtime.h>

#define TILE_ATOMS 10000               // 10 tiles for 100K atoms
#define TILE_FLOATS (TILE_ATOMS * 2)   // 2 channels/block: 80000 B LDS
#define BLOCK 1024
#define CPX 3                          // chunks per XCD
#define CHUNKS 24                      // 8 XCDs * CPX
#define RSQRT2 0.70710678118654752440f

typedef float v2f __attribute__((ext_vector_type(2)));

// Packed 2xf32 memory-side atomic add where available; else scalar pair.
__device__ __forceinline__ void atomic_add2(float* p, float a, float b) {
#if __has_builtin(__builtin_amdgcn_global_atomic_fadd_v2f32)
    v2f v = {a, b};
    __builtin_amdgcn_global_atomic_fadd_v2f32((v2f*)p, v);
#else
    unsafeAtomicAdd(p + 0, a);
    unsafeAtomicAdd(p + 1, b);
#endif
}

// Detect whether neighbor_indices is int64 or int32 (odd u32 words all zero
// => int64 high halves). Plain-store flag is replay-safe: even a stale read
// returns the same constant value (r3 analysis).
__global__ void detect_idx64_kernel(const unsigned int* __restrict__ idx_u32,
                                    int* __restrict__ flag) {
    __shared__ int nonzero;
    if (threadIdx.x == 0) nonzero = 0;
    __syncthreads();
    unsigned int v = idx_u32[2 * (threadIdx.x +   0) + 1]
                   | idx_u32[2 * (threadIdx.x + 256) + 1]
                   | idx_u32[2 * (threadIdx.x + 512) + 1]
                   | idx_u32[2 * (threadIdx.x + 768) + 1];
    if (v != 0u) atomicAdd(&nonzero, 1);
    __syncthreads();
    if (threadIdx.x == 0) *flag = (nonzero == 0) ? 1 : 0;  // 1 => int64
}

// Channel-split scan: this block accumulates channels [2h, 2h+1] of tile t.
// Contiguous-4 edges per lane: 1 float4 dist load + dense idx loads.
template <bool F64>
__device__ __forceinline__ void scan_chunk(
    const void* __restrict__ idx, const float* __restrict__ dist,
    const float2* __restrict__ charges2, float* __restrict__ tile,
    int tbase, int h, int e0, int e1)
{
    int ec = e0 + ((e1 - e0) & ~3);       // 4-aligned main region
    for (int e4 = e0 + (int)threadIdx.x * 4; e4 < ec; e4 += BLOCK * 4) {
        int a[4], b[4];
        if (F64) {
            #pragma unroll
            for (int k = 0; k < 4; ++k) {
                longlong2 w = ((const longlong2*)idx)[e4 + k];
                a[k] = (int)w.x; b[k] = (int)w.y;
            }
        } else {
            int4 w01 = ((const int4*)idx)[(e4 >> 1) + 0];   // edges e4,e4+1
            int4 w23 = ((const int4*)idx)[(e4 >> 1) + 1];   // edges e4+2,e4+3
            a[0] = w01.x; b[0] = w01.y; a[1] = w01.z; b[1] = w01.w;
            a[2] = w23.x; b[2] = w23.y; a[3] = w23.z; b[3] = w23.w;
        }
        float4 dv = *(const float4*)(dist + e4);            // e4 is 4-aligned
        float d[4] = {dv.x, dv.y, dv.z, dv.w};
        float q[4];
        #pragma unroll
        for (int k = 0; k < 4; ++k)
            q[k] = 0.5f * erfcf(d[k] * RSQRT2) * __builtin_amdgcn_rcpf(d[k]);
        #pragma unroll
        for (int k = 0; k < 4; ++k) {
            unsigned ri = (unsigned)(a[k] - tbase);
            unsigned rj = (unsigned)(b[k] - tbase);
            if (ri < TILE_ATOMS) {
                float2 g = charges2[b[k] * 2 + h];          // other endpoint
                atomicAdd(&tile[ri * 2 + 0], g.x * q[k]);
                atomicAdd(&tile[ri * 2 + 1], g.y * q[k]);
            }
            if (rj < TILE_ATOMS) {
                float2 g = charges2[a[k] * 2 + h];
                atomicAdd(&tile[rj * 2 + 0], g.x * q[k]);
                atomicAdd(&tile[rj * 2 + 1], g.y * q[k]);
            }
        }
    }
    for (int e = ec + (int)threadIdx.x; e < e1; e += BLOCK) {   // tail < 4
        int a, b;
        if (F64) { longlong2 w = ((const longlong2*)idx)[e]; a = (int)w.x; b = (int)w.y; }
        else     { int2      w = ((const int2*)idx)[e];      a = w.x;      b = w.y; }
        unsigned ri = (unsigned)(a - tbase), rj = (unsigned)(b - tbase);
        if (ri < TILE_ATOMS || rj < TILE_ATOMS) {
            float d = dist[e];
            float q = 0.5f * erfcf(d * RSQRT2) * __builtin_amdgcn_rcpf(d);
            if (ri < TILE_ATOMS) {
                float2 g = charges2[b * 2 + h];
                atomicAdd(&tile[ri * 2 + 0], g.x * q);
                atomicAdd(&tile[ri * 2 + 1], g.y * q);
            }
            if (rj < TILE_ATOMS) {
                float2 g = charges2[a * 2 + h];
                atomicAdd(&tile[rj * 2 + 0], g.x * q);
                atomicAdd(&tile[rj * 2 + 1], g.y * q);
            }
        }
    }
}

// Block = (tile t, channel-half h, chunk c). 80KB LDS -> 2 blocks/CU ->
// 32 waves/CU (vs 16): doubles latency-hiding concurrency, which r6/r8
// counters (VALU 29%, no pipe saturated) indicate is the limiter.
// XCD-affine chunk mapping keeps the read window L2-local (r5/r6).
__global__ __launch_bounds__(BLOCK, 8) void fused_tile_kernel(
    const float2* __restrict__ charges2, const void* __restrict__ idx,
    const float* __restrict__ dist, float* __restrict__ out,
    const int* __restrict__ flag64,
    int n_edges, int n_atoms, int ntiles, int epc)
{
    __shared__ float tile[TILE_FLOATS];
    int x   = blockIdx.x & 7;             // XCD (round-robin dispatch, m09)
    int m   = blockIdx.x >> 3;
    int nth = ntiles * 2;                 // (tile, half) pairs
    int cw  = m / nth;                    // 0..CPX-1
    int rem = m - cw * nth;
    int t   = rem >> 1;
    int h   = rem & 1;
    int c   = x * CPX + cw;
    int tbase = t * TILE_ATOMS;
    for (int i = threadIdx.x; i < TILE_FLOATS; i += BLOCK) tile[i] = 0.f;
    bool f64 = (*flag64 != 0);
    __syncthreads();

    int e0 = c * epc;
    int e1 = min(n_edges, e0 + epc);
    if (e0 < e1) {
        if (f64) scan_chunk<true >(idx, dist, charges2, tile, tbase, h, e0, e1);
        else     scan_chunk<false>(idx, dist, charges2, tile, tbase, h, e0, e1);
    }
    __syncthreads();

    // Flush this block's 2 channels with HW atomics (replay-safe path).
    const float2* src = (const float2*)tile;
    for (int r = threadIdx.x; r < TILE_ATOMS; r += BLOCK) {
        int a = tbase + r;
        if (a >= n_atoms) break;
        float2 v = src[r];                                  // ds_read_b64
        if (v.x != 0.f || v.y != 0.f)
            atomic_add2(out + (size_t)a * 4 + h * 2, v.x, v.y);
    }
}

extern "C" void kernel_launch(void* const* d_in, const int* in_sizes, int n_in,
                              void* d_out, int out_size, void* d_ws, size_t ws_size,
                              hipStream_t stream) {
    const float2* charges2 = (const float2*)d_in[0];
    const void*   idx      = d_in[1];
    const float*  dist     = (const float*)d_in[2];
    int n_edges = in_sizes[2];
    int n_atoms = in_sizes[0] / 4;
    int ntiles  = (n_atoms + TILE_ATOMS - 1) / TILE_ATOMS;   // 10
    int epc     = (((n_edges + CHUNKS - 1) / CHUNKS) + 3) & ~3;  // 4-aligned
    int* flag   = (int*)d_ws;

    (void)hipMemsetAsync(d_out, 0, (size_t)out_size * sizeof(float), stream);
    detect_idx64_kernel<<<1, 256, 0, stream>>>((const unsigned int*)idx, flag);
    fused_tile_kernel<<<ntiles * 2 * CHUNKS, BLOCK, 0, stream>>>(
        charges2, idx, dist, (float*)d_out, flag, n_edges, n_atoms, ntiles, epc);
}

// Round 10
// 399.198 us; speedup vs baseline: 1.1268x; 1.0211x over previous
//
#include <hip/hip_runtime.h>

#define TILE_ATOMS 10000               // 10 tiles for 100K atoms
#define TILE_FLOATS (TILE_ATOMS * 2)   // 2 channels/block: 80000 B LDS
#define BLOCK 1024
#define CPX 3                          // chunks per XCD
#define CHUNKS 24                      // 8 XCDs * CPX
#define RSQRT2 0.70710678118654752440f

typedef float v2f __attribute__((ext_vector_type(2)));

// Packed 2xf32 memory-side atomic add where available; else scalar pair.
__device__ __forceinline__ void atomic_add2(float* p, float a, float b) {
#if __has_builtin(__builtin_amdgcn_global_atomic_fadd_v2f32)
    v2f v = {a, b};
    __builtin_amdgcn_global_atomic_fadd_v2f32((v2f*)p, v);
#else
    unsafeAtomicAdd(p + 0, a);
    unsafeAtomicAdd(p + 1, b);
#endif
}

// pot(d) = 0.5*erfc(d/sqrt(2))/d via Abramowitz-Stegun 7.1.26 (|eps|<=1.5e-7):
// erfc(x) = t*(a1+t*(a2+t*(a3+t*(a4+t*a5))))*exp(-x^2), t=1/(1+0.3275911x).
// The 0.5 is folded into the coefficients; exp(-x^2)=exp(-d^2/2) uses the HW
// v_exp_f32 via __expf. ~15 VALU inst vs ~30 for libm erfcf — r9 showed the
// scan is VALU-issue-bound on exactly this (VALUBusy 58%, 236us of erfc).
__device__ __forceinline__ float pot_half(float d) {
    float x = d * RSQRT2;
    float t = __builtin_amdgcn_rcpf(fmaf(0.3275911f, x, 1.0f));
    float p = fmaf(t, 0.5307027145f, -0.7265760135f);   // 0.5*a5, 0.5*a4
    p = fmaf(t, p, 0.7107068705f);                      // 0.5*a3
    p = fmaf(t, p, -0.142248368f);                      // 0.5*a2
    p = fmaf(t, p, 0.127414796f);                       // 0.5*a1
    p *= t;
    return p * __expf(-0.5f * d * d) * __builtin_amdgcn_rcpf(d);
}

// Detect whether neighbor_indices is int64 or int32 (odd u32 words all zero
// => int64 high halves). Plain-store flag is replay-tolerant here (stale
// poison 0xAA != 0 decodes as int64, which matches the data).
__global__ void detect_idx64_kernel(const unsigned int* __restrict__ idx_u32,
                                    int* __restrict__ flag) {
    __shared__ int nonzero;
    if (threadIdx.x == 0) nonzero = 0;
    __syncthreads();
    unsigned int v = idx_u32[2 * (threadIdx.x +   0) + 1]
                   | idx_u32[2 * (threadIdx.x + 256) + 1]
                   | idx_u32[2 * (threadIdx.x + 512) + 1]
                   | idx_u32[2 * (threadIdx.x + 768) + 1];
    if (v != 0u) atomicAdd(&nonzero, 1);
    __syncthreads();
    if (threadIdx.x == 0) *flag = (nonzero == 0) ? 1 : 0;  // 1 => int64
}

// Channel-split scan: this block accumulates channels [2h, 2h+1] of tile t.
// Contiguous-4 edges per lane: 1 float4 dist load + dense idx loads.
template <bool F64>
__device__ __forceinline__ void scan_chunk(
    const void* __restrict__ idx, const float* __restrict__ dist,
    const float2* __restrict__ charges2, float* __restrict__ tile,
    int tbase, int h, int e0, int e1)
{
    int ec = e0 + ((e1 - e0) & ~3);       // 4-aligned main region
    for (int e4 = e0 + (int)threadIdx.x * 4; e4 < ec; e4 += BLOCK * 4) {
        int a[4], b[4];
        if (F64) {
            #pragma unroll
            for (int k = 0; k < 4; ++k) {
                longlong2 w = ((const longlong2*)idx)[e4 + k];
                a[k] = (int)w.x; b[k] = (int)w.y;
            }
        } else {
            int4 w01 = ((const int4*)idx)[(e4 >> 1) + 0];   // edges e4,e4+1
            int4 w23 = ((const int4*)idx)[(e4 >> 1) + 1];   // edges e4+2,e4+3
            a[0] = w01.x; b[0] = w01.y; a[1] = w01.z; b[1] = w01.w;
            a[2] = w23.x; b[2] = w23.y; a[3] = w23.z; b[3] = w23.w;
        }
        float4 dv = *(const float4*)(dist + e4);            // e4 is 4-aligned
        float d[4] = {dv.x, dv.y, dv.z, dv.w};
        float q[4];
        #pragma unroll
        for (int k = 0; k < 4; ++k) q[k] = pot_half(d[k]);
        #pragma unroll
        for (int k = 0; k < 4; ++k) {
            unsigned ri = (unsigned)(a[k] - tbase);
            unsigned rj = (unsigned)(b[k] - tbase);
            if (ri < TILE_ATOMS) {
                float2 g = charges2[b[k] * 2 + h];          // other endpoint
                atomicAdd(&tile[ri * 2 + 0], g.x * q[k]);
                atomicAdd(&tile[ri * 2 + 1], g.y * q[k]);
            }
            if (rj < TILE_ATOMS) {
                float2 g = charges2[a[k] * 2 + h];
                atomicAdd(&tile[rj * 2 + 0], g.x * q[k]);
                atomicAdd(&tile[rj * 2 + 1], g.y * q[k]);
            }
        }
    }
    for (int e = ec + (int)threadIdx.x; e < e1; e += BLOCK) {   // tail < 4
        int a, b;
        if (F64) { longlong2 w = ((const longlong2*)idx)[e]; a = (int)w.x; b = (int)w.y; }
        else     { int2      w = ((const int2*)idx)[e];      a = w.x;      b = w.y; }
        unsigned ri = (unsigned)(a - tbase), rj = (unsigned)(b - tbase);
        if (ri < TILE_ATOMS || rj < TILE_ATOMS) {
            float q = pot_half(dist[e]);
            if (ri < TILE_ATOMS) {
                float2 g = charges2[b * 2 + h];
                atomicAdd(&tile[ri * 2 + 0], g.x * q);
                atomicAdd(&tile[ri * 2 + 1], g.y * q);
            }
            if (rj < TILE_ATOMS) {
                float2 g = charges2[a * 2 + h];
                atomicAdd(&tile[rj * 2 + 0], g.x * q);
                atomicAdd(&tile[rj * 2 + 1], g.y * q);
            }
        }
    }
}

// Block = (tile t, channel-half h, chunk c). 80KB LDS -> 2 blocks/CU ->
// 32 waves/CU. XCD-affine chunk mapping keeps the read window L2-local
// (r5/r6: FETCH 334->44MB). Flush via HW atomics (replay-safe; plain
// cross-kernel ws handoff is NOT — r3 lesson).
__global__ __launch_bounds__(BLOCK, 8) void fused_tile_kernel(
    const float2* __restrict__ charges2, const void* __restrict__ idx,
    const float* __restrict__ dist, float* __restrict__ out,
    const int* __restrict__ flag64,
    int n_edges, int n_atoms, int ntiles, int epc)
{
    __shared__ float tile[TILE_FLOATS];
    int x   = blockIdx.x & 7;             // XCD (round-robin dispatch, m09)
    int m   = blockIdx.x >> 3;
    int nth = ntiles * 2;                 // (tile, half) pairs
    int cw  = m / nth;                    // 0..CPX-1
    int rem = m - cw * nth;
    int t   = rem >> 1;
    int h   = rem & 1;
    int c   = x * CPX + cw;
    int tbase = t * TILE_ATOMS;
    for (int i = threadIdx.x; i < TILE_FLOATS; i += BLOCK) tile[i] = 0.f;
    bool f64 = (*flag64 != 0);
    __syncthreads();

    int e0 = c * epc;
    int e1 = min(n_edges, e0 + epc);
    if (e0 < e1) {
        if (f64) scan_chunk<true >(idx, dist, charges2, tile, tbase, h, e0, e1);
        else     scan_chunk<false>(idx, dist, charges2, tile, tbase, h, e0, e1);
    }
    __syncthreads();

    // Flush this block's 2 channels with HW atomics (replay-safe path).
    const float2* src = (const float2*)tile;
    for (int r = threadIdx.x; r < TILE_ATOMS; r += BLOCK) {
        int a = tbase + r;
        if (a >= n_atoms) break;
        float2 v = src[r];                                  // ds_read_b64
        if (v.x != 0.f || v.y != 0.f)
            atomic_add2(out + (size_t)a * 4 + h * 2, v.x, v.y);
    }
}

extern "C" void kernel_launch(void* const* d_in, const int* in_sizes, int n_in,
                              void* d_out, int out_size, void* d_ws, size_t ws_size,
                              hipStream_t stream) {
    const float2* charges2 = (const float2*)d_in[0];
    const void*   idx      = d_in[1];
    const float*  dist     = (const float*)d_in[2];
    int n_edges = in_sizes[2];
    int n_atoms = in_sizes[0] / 4;
    int ntiles  = (n_atoms + TILE_ATOMS - 1) / TILE_ATOMS;   // 10
    int epc     = (((n_edges + CHUNKS - 1) / CHUNKS) + 3) & ~3;  // 4-aligned
    int* flag   = (int*)d_ws;

    (void)hipMemsetAsync(d_out, 0, (size_t)out_size * sizeof(float), stream);
    detect_idx64_kernel<<<1, 256, 0, stream>>>((const unsigned int*)idx, flag);
    fused_tile_kernel<<<ntiles * 2 * CHUNKS, BLOCK, 0, stream>>>(
        charges2, idx, dist, (float*)d_out, flag, n_edges, n_atoms, ntiles, epc);
}